// Round 3
// baseline (147.085 us; speedup 1.0000x reference)
//
#include <hip/hip_runtime.h>
#include <hip/hip_fp16.h>

#define DDIM 64
#define MAXNS 2048          // max slices (nodes/256) handled by the new path
#define PART_TPB 256
#define PART_EPT 16
#define PART_EPB (PART_TPB * PART_EPT)   // 4096 edges per block

__device__ __forceinline__ float atomAddF(float* p, float v) {
    return unsafeAtomicAdd(p, v);   // HW global_atomic_add_f32 on gfx950
}

// ================= CSR BUILD: two-level counting sort by dst>>8 =================

// Pass 1: per-slice edge counts (LDS-aggregated histogram)
__global__ void slice_count_kernel(const int* __restrict__ dst, int* __restrict__ sliceCnt,
                                   int nE, int NS) {
    __shared__ int lh[MAXNS];
    int t = threadIdx.x;
    int blockBase = blockIdx.x * PART_EPB;
    for (int i = t; i < NS; i += PART_TPB) lh[i] = 0;
    __syncthreads();
    #pragma unroll
    for (int c = 0; c < 4; ++c) {
        int e0 = blockBase + (c * PART_TPB + t) * 4;
        if (e0 + 3 < nE) {
            int4 b = *(const int4*)(dst + e0);
            atomicAdd(&lh[b.x >> 8], 1); atomicAdd(&lh[b.y >> 8], 1);
            atomicAdd(&lh[b.z >> 8], 1); atomicAdd(&lh[b.w >> 8], 1);
        } else {
            for (int j = 0; j < 4; ++j) {
                int e = e0 + j;
                if (e < nE) atomicAdd(&lh[dst[e] >> 8], 1);
            }
        }
    }
    __syncthreads();
    for (int i = t; i < NS; i += PART_TPB)
        if (lh[i]) atomicAdd(&sliceCnt[i], lh[i]);
}

// Pass 2 (1 block): exclusive scan of slice counts -> sliceBase[] (persistent)
// and scnt[] reused as running cursors for partition. Fused Wp build.
__global__ void slice_scan_wp_kernel(int* __restrict__ scnt, int* __restrict__ sbase,
                                     int NS, int nE,
                                     const float* __restrict__ W, const float* __restrict__ lamda_p,
                                     const int* __restrict__ layer_p, float* __restrict__ Wp) {
    __shared__ int sdata[512];
    int t = threadIdx.x;
    int base = t * 4;
    int v[4];
    #pragma unroll
    for (int j = 0; j < 4; ++j) {
        int idx = base + j;
        v[j] = (idx < NS) ? scnt[idx] : 0;
    }
    int local = v[0] + v[1] + v[2] + v[3];
    sdata[t] = local;
    __syncthreads();
    for (int off = 1; off < 512; off <<= 1) {
        int y = (t >= off) ? sdata[t - off] : 0;
        __syncthreads();
        sdata[t] += y;
        __syncthreads();
    }
    int run = sdata[t] - local;
    #pragma unroll
    for (int j = 0; j < 4; ++j) {
        int idx = base + j;
        if (idx < NS) { sbase[idx] = run; scnt[idx] = run; }
        run += v[j];
    }
    if (t == 0) sbase[NS] = nE;

    float lam = lamda_p[0];
    int lb = layer_p[0];
    float layerf = (lb > 0 && lb < (1 << 23)) ? (float)lb : __int_as_float(lb);
    float beta = logf(lam / layerf + 1.0f);
    for (int i = t; i < DDIM * DDIM; i += 512) {
        int k = i >> 6, d = i & 63;
        float w = beta * W[i];
        if (k == d) w += (1.0f - beta);
        Wp[i] = w;
    }
}

// Pass 3: scatter packed (src<<8 | dstLow) into per-slice staging regions.
__global__ void partition_kernel(const int* __restrict__ src, const int* __restrict__ dst,
                                 int* __restrict__ cursor, unsigned* __restrict__ staging,
                                 int nE, int NS) {
    __shared__ int lh[MAXNS];
    __shared__ int lbase[MAXNS];
    int t = threadIdx.x;
    int blockBase = blockIdx.x * PART_EPB;
    for (int i = t; i < NS; i += PART_TPB) lh[i] = 0;
    __syncthreads();

    int se[PART_EPT]; int de[PART_EPT];
    #pragma unroll
    for (int c = 0; c < 4; ++c) {
        int e0 = blockBase + (c * PART_TPB + t) * 4;
        if (e0 + 3 < nE) {
            int4 a = *(const int4*)(src + e0);
            int4 b = *(const int4*)(dst + e0);
            se[4*c+0] = a.x; se[4*c+1] = a.y; se[4*c+2] = a.z; se[4*c+3] = a.w;
            de[4*c+0] = b.x; de[4*c+1] = b.y; de[4*c+2] = b.z; de[4*c+3] = b.w;
        } else {
            #pragma unroll
            for (int j = 0; j < 4; ++j) {
                int e = e0 + j;
                se[4*c+j] = (e < nE) ? src[e] : 0;
                de[4*c+j] = (e < nE) ? dst[e] : -1;
            }
        }
    }
    #pragma unroll
    for (int k = 0; k < PART_EPT; ++k)
        if (de[k] >= 0) atomicAdd(&lh[de[k] >> 8], 1);
    __syncthreads();
    for (int i = t; i < NS; i += PART_TPB) {
        int c = lh[i];
        if (c) lbase[i] = atomicAdd(&cursor[i], c);
        lh[i] = 0;
    }
    __syncthreads();
    #pragma unroll
    for (int k = 0; k < PART_EPT; ++k) {
        int d = de[k];
        if (d >= 0) {
            int sl = d >> 8;
            int off = atomicAdd(&lh[sl], 1);
            staging[lbase[sl] + off] = ((unsigned)se[k] << 8) | (unsigned)(d & 255);
        }
    }
}

// Pass 4: one block per slice. Histogram 256 local nodes (== degI), LDS scan
// (== row_end), write normv, then scatter eidx inside an L2-resident window.
__global__ void bin_fill_kernel(const unsigned* __restrict__ staging, const int* __restrict__ sbase,
                                int* __restrict__ degI, float* __restrict__ normv,
                                int* __restrict__ row_end, int* __restrict__ eidx, int nN) {
    __shared__ int cnt[256];
    __shared__ int pos[256];
    int s = blockIdx.x;
    int t = threadIdx.x;
    int b0 = sbase[s], b1 = sbase[s + 1];
    cnt[t] = 0;
    __syncthreads();
    for (int j = b0 + t; j < b1; j += 256) {
        unsigned p = staging[j];
        atomicAdd(&cnt[p & 255], 1);
    }
    __syncthreads();
    int c = cnt[t];
    pos[t] = c;
    __syncthreads();
    for (int off = 1; off < 256; off <<= 1) {
        int y = (t >= off) ? pos[t - off] : 0;
        __syncthreads();
        pos[t] += y;
        __syncthreads();
    }
    int inc = pos[t];
    int exc = inc - c;
    int node = (s << 8) + t;
    if (node < nN) {
        degI[node] = c;
        normv[node] = rsqrtf(fmaxf((float)c, 1.0f));
        row_end[node] = b0 + inc;
    }
    pos[t] = b0 + exc;
    __syncthreads();
    for (int j = b0 + t; j < b1; j += 256) {
        unsigned p = staging[j];
        int q = atomicAdd(&pos[p & 255], 1);
        eidx[q] = (int)(p >> 8);
    }
}

// featS(fp16) = feat * norm[node]; lane holds 4 dims -> 8B (uint2) per lane
__global__ void scale_kernel(const float4* __restrict__ feat4, const float* __restrict__ normv,
                             uint2* __restrict__ featS2, int nN) {
    int b = blockIdx.x, t = threadIdx.x;
    int node = b * 16 + (t >> 4);
    int r = t & 15;
    if (node < nN) {
        float nv = normv[node];
        float4 v = feat4[(size_t)node * 16 + r];
        __half2 h0 = __floats2half2_rn(v.x * nv, v.y * nv);
        __half2 h1 = __floats2half2_rn(v.z * nv, v.w * nv);
        uint2 u;
        u.x = *(unsigned*)&h0;
        u.y = *(unsigned*)&h1;
        featS2[(size_t)node * 16 + r] = u;
    }
}

// ================= OLD CSR BUILD (fallback tier) =================

__global__ void deg_int_kernel(const int* __restrict__ dst, int* __restrict__ degI, int nE) {
    int i = blockIdx.x * blockDim.x + threadIdx.x;
    int base = i * 4;
    if (base + 3 < nE) {
        int4 d = *(const int4*)(dst + base);
        atomicAdd(&degI[d.x], 1); atomicAdd(&degI[d.y], 1);
        atomicAdd(&degI[d.z], 1); atomicAdd(&degI[d.w], 1);
    } else {
        for (int j = base; j < nE; ++j) atomicAdd(&degI[dst[j]], 1);
    }
}

#define SCAN_BLOCK 256
#define SCAN_CHUNK 1024

__global__ void scan1_kernel(const int* __restrict__ degI, int* __restrict__ row_start,
                             float* __restrict__ normv, int* __restrict__ blockSums, int nN) {
    __shared__ int sdata[SCAN_BLOCK];
    int t = threadIdx.x;
    int base = blockIdx.x * SCAN_CHUNK + t * 4;
    int v[4];
    #pragma unroll
    for (int j = 0; j < 4; ++j) {
        int idx = base + j;
        v[j] = (idx < nN) ? degI[idx] : 0;
    }
    int local = v[0] + v[1] + v[2] + v[3];
    sdata[t] = local;
    __syncthreads();
    for (int off = 1; off < SCAN_BLOCK; off <<= 1) {
        int y = (t >= off) ? sdata[t - off] : 0;
        __syncthreads();
        sdata[t] += y;
        __syncthreads();
    }
    int inc = sdata[t];
    int exc = inc - local;
    if (t == SCAN_BLOCK - 1) blockSums[blockIdx.x] = inc;
    int run = exc;
    #pragma unroll
    for (int j = 0; j < 4; ++j) {
        int idx = base + j;
        if (idx < nN) {
            row_start[idx] = run;
            normv[idx] = rsqrtf(fmaxf((float)v[j], 1.0f));
        }
        run += v[j];
    }
}

__global__ void scan2_wp_kernel(int* __restrict__ blockSums, int nb,
                                const float* __restrict__ W, const float* __restrict__ lamda_p,
                                const int* __restrict__ layer_p, float* __restrict__ Wp) {
    __shared__ int sdata[SCAN_BLOCK];
    int t = threadIdx.x;
    int v = (t < nb) ? blockSums[t] : 0;
    sdata[t] = v;
    __syncthreads();
    for (int off = 1; off < SCAN_BLOCK; off <<= 1) {
        int y = (t >= off) ? sdata[t - off] : 0;
        __syncthreads();
        sdata[t] += y;
        __syncthreads();
    }
    if (t < nb) blockSums[t] = sdata[t] - v;

    float lam = lamda_p[0];
    int lb = layer_p[0];
    float layerf = (lb > 0 && lb < (1 << 23)) ? (float)lb : __int_as_float(lb);
    float beta = logf(lam / layerf + 1.0f);
    for (int i = t; i < DDIM * DDIM; i += SCAN_BLOCK) {
        int k = i >> 6, d = i & 63;
        float w = beta * W[i];
        if (k == d) w += (1.0f - beta);
        Wp[i] = w;
    }
}

// add block offsets to row_start AND produce featS(fp16)
__global__ void scan3_scale_kernel(int* __restrict__ row_start, const int* __restrict__ blockSums,
                                   const float4* __restrict__ feat4, const float* __restrict__ normv,
                                   uint2* __restrict__ featS2, int nN) {
    int b = blockIdx.x, t = threadIdx.x;
    int node = b * 16 + (t >> 4);
    int r = t & 15;
    if (node < nN) {
        float nv = normv[node];
        float4 v = feat4[(size_t)node * 16 + r];
        __half2 h0 = __floats2half2_rn(v.x * nv, v.y * nv);
        __half2 h1 = __floats2half2_rn(v.z * nv, v.w * nv);
        uint2 u;
        u.x = *(unsigned*)&h0;
        u.y = *(unsigned*)&h1;
        featS2[(size_t)node * 16 + r] = u;
    }
    if (t < 16) {
        int n2 = b * 16 + t;
        if (n2 < nN) row_start[n2] += blockSums[n2 >> 10];
    }
}

__global__ void scan3_kernel(int* __restrict__ row_start, const int* __restrict__ blockSums, int nN) {
    int i = blockIdx.x * blockDim.x + threadIdx.x;
    if (i < nN) row_start[i] += blockSums[i >> 10];
}

__global__ void fill_kernel(const int* __restrict__ src, const int* __restrict__ dst,
                            int* __restrict__ row_start, int* __restrict__ eidx, int nE) {
    int i = blockIdx.x * blockDim.x + threadIdx.x;
    int base = i * 4;
    if (base + 3 < nE) {
        int4 s = *(const int4*)(src + base);
        int4 d = *(const int4*)(dst + base);
        eidx[atomicAdd(&row_start[d.x], 1)] = s.x;
        eidx[atomicAdd(&row_start[d.y], 1)] = s.y;
        eidx[atomicAdd(&row_start[d.z], 1)] = s.z;
        eidx[atomicAdd(&row_start[d.w], 1)] = s.w;
    } else {
        for (int j = base; j < nE; ++j) {
            int tt = dst[j];
            int p = atomicAdd(&row_start[tt], 1);
            eidx[p] = src[j];
        }
    }
}

// ---------------- fused gather + epilogue (wave per node, 8x8 lane layout) ----------------
// Lane: g=lane>>3 (edge group, edges e%8==g), r=lane&7 (dims [8r, 8r+8)).
// HALF=true: featS fp16 rows = 128B = 8 lanes x uint4 -> ONE 16B load per lane per edge
//            (halves scattered-request count vs 4x16 layout; 16 rows in flight/wave).
// HALF=false: fp32 rows = 256B -> two float4 loads per lane per edge.
// sW rotated layout: float4 col' = (c + 2*(k>>3)) & 15  -> <=2-way LDS conflict (free).
template<bool HALF>
__global__ void gather_kernel(const void* __restrict__ featv_, const float4* __restrict__ feat04,
                              const float* __restrict__ normv, const int* __restrict__ degI,
                              const int* __restrict__ row_end, const int* __restrict__ eidx,
                              const float* __restrict__ Wp, const float* __restrict__ alpha_p,
                              float4* __restrict__ out4, int nN) {
    __shared__ float4 sW[DDIM * 16];   // 16 KiB, rotated by row-group
    const float4* Wp4 = (const float4*)Wp;
    for (int i = threadIdx.x; i < DDIM * 16; i += blockDim.x) {
        int k = i >> 4, c = i & 15;
        sW[k * 16 + ((c + 2 * (k >> 3)) & 15)] = Wp4[i];
    }
    __syncthreads();

    const float4* featF = (const float4*)featv_;
    const uint4*  featH = (const uint4*)featv_;

    int lane = threadIdx.x & 63;
    int w = threadIdx.x >> 6;
    int g = lane >> 3;   // 0..7
    int r = lane & 7;    // 0..7
    float alpha = alpha_p[0];

    for (int n = blockIdx.x * 4 + w; n < nN; n += gridDim.x * 4) {
        int end = row_end[n];
        int deg = degI[n];
        int start = end - deg;

        float4 accA = make_float4(0.f, 0.f, 0.f, 0.f);
        float4 accB = make_float4(0.f, 0.f, 0.f, 0.f);

        for (int j0 = start; j0 < end; j0 += 64) {
            int m = end - j0; if (m > 64) m = 64;
            int sIdx = 0;
            float nv = 1.0f;
            if (lane < m) {
                sIdx = eidx[j0 + lane];
                if (!HALF) nv = normv[sIdx];
            }
            int nt = (m + 7) >> 3;
            int t = 0;
            // 4-wide tier: 4 independent row loads in flight per lane
            for (; t + 4 <= nt; t += 4) {
                int e0 = 8*t + g, e1 = e0 + 8, e2 = e0 + 16, e3 = e0 + 24;
                int s0 = __shfl(sIdx, e0, 64);
                int s1 = __shfl(sIdx, e1, 64);
                int s2 = __shfl(sIdx, e2, 64);
                int s3 = __shfl(sIdx, e3, 64);
                float w0 = (e0 < m) ? 1.0f : 0.0f;
                float w1 = (e1 < m) ? 1.0f : 0.0f;
                float w2 = (e2 < m) ? 1.0f : 0.0f;
                float w3 = (e3 < m) ? 1.0f : 0.0f;
                if (HALF) {
                    uint4 u0 = featH[(size_t)s0 * 8 + r];
                    uint4 u1 = featH[(size_t)s1 * 8 + r];
                    uint4 u2 = featH[(size_t)s2 * 8 + r];
                    uint4 u3 = featH[(size_t)s3 * 8 + r];
                    #define ACC_H(u, ww) { \
                        float2 p0 = __half22float2(*(const __half2*)&(u).x); \
                        float2 p1 = __half22float2(*(const __half2*)&(u).y); \
                        float2 p2 = __half22float2(*(const __half2*)&(u).z); \
                        float2 p3 = __half22float2(*(const __half2*)&(u).w); \
                        accA.x = fmaf(p0.x, ww, accA.x); accA.y = fmaf(p0.y, ww, accA.y); \
                        accA.z = fmaf(p1.x, ww, accA.z); accA.w = fmaf(p1.y, ww, accA.w); \
                        accB.x = fmaf(p2.x, ww, accB.x); accB.y = fmaf(p2.y, ww, accB.y); \
                        accB.z = fmaf(p3.x, ww, accB.z); accB.w = fmaf(p3.y, ww, accB.w); }
                    ACC_H(u0, w0) ACC_H(u1, w1) ACC_H(u2, w2) ACC_H(u3, w3)
                } else {
                    w0 *= __shfl(nv, e0, 64); w1 *= __shfl(nv, e1, 64);
                    w2 *= __shfl(nv, e2, 64); w3 *= __shfl(nv, e3, 64);
                    float4 a0 = featF[(size_t)s0 * 16 + 2*r], a1 = featF[(size_t)s0 * 16 + 2*r + 1];
                    float4 b0 = featF[(size_t)s1 * 16 + 2*r], b1 = featF[(size_t)s1 * 16 + 2*r + 1];
                    float4 c0 = featF[(size_t)s2 * 16 + 2*r], c1 = featF[(size_t)s2 * 16 + 2*r + 1];
                    float4 d0 = featF[(size_t)s3 * 16 + 2*r], d1 = featF[(size_t)s3 * 16 + 2*r + 1];
                    #define ACC_F(x0, x1, ww) { \
                        accA.x = fmaf((x0).x, ww, accA.x); accA.y = fmaf((x0).y, ww, accA.y); \
                        accA.z = fmaf((x0).z, ww, accA.z); accA.w = fmaf((x0).w, ww, accA.w); \
                        accB.x = fmaf((x1).x, ww, accB.x); accB.y = fmaf((x1).y, ww, accB.y); \
                        accB.z = fmaf((x1).z, ww, accB.z); accB.w = fmaf((x1).w, ww, accB.w); }
                    ACC_F(a0, a1, w0) ACC_F(b0, b1, w1) ACC_F(c0, c1, w2) ACC_F(d0, d1, w3)
                }
            }
            for (; t + 2 <= nt; t += 2) {
                int e0 = 8*t + g, e1 = e0 + 8;
                int s0 = __shfl(sIdx, e0, 64);
                int s1 = __shfl(sIdx, e1, 64);
                float w0 = (e0 < m) ? 1.0f : 0.0f;
                float w1 = (e1 < m) ? 1.0f : 0.0f;
                if (HALF) {
                    uint4 u0 = featH[(size_t)s0 * 8 + r];
                    uint4 u1 = featH[(size_t)s1 * 8 + r];
                    ACC_H(u0, w0) ACC_H(u1, w1)
                } else {
                    w0 *= __shfl(nv, e0, 64); w1 *= __shfl(nv, e1, 64);
                    float4 a0 = featF[(size_t)s0 * 16 + 2*r], a1 = featF[(size_t)s0 * 16 + 2*r + 1];
                    float4 b0 = featF[(size_t)s1 * 16 + 2*r], b1 = featF[(size_t)s1 * 16 + 2*r + 1];
                    ACC_F(a0, a1, w0) ACC_F(b0, b1, w1)
                }
            }
            if (t < nt) {
                int e0 = 8*t + g;
                int s0 = __shfl(sIdx, e0, 64);
                float w0 = (e0 < m) ? 1.0f : 0.0f;
                if (HALF) {
                    uint4 u0 = featH[(size_t)s0 * 8 + r];
                    ACC_H(u0, w0)
                } else {
                    w0 *= __shfl(nv, e0, 64);
                    float4 a0 = featF[(size_t)s0 * 16 + 2*r], a1 = featF[(size_t)s0 * 16 + 2*r + 1];
                    ACC_F(a0, a1, w0)
                }
            }
        }

        // combine the 8 groups' partial sums (lane bits 3,4,5)
        #define RED(acc) \
            acc.x += __shfl_xor(acc.x, 8, 64);  acc.y += __shfl_xor(acc.y, 8, 64); \
            acc.z += __shfl_xor(acc.z, 8, 64);  acc.w += __shfl_xor(acc.w, 8, 64); \
            acc.x += __shfl_xor(acc.x, 16, 64); acc.y += __shfl_xor(acc.y, 16, 64); \
            acc.z += __shfl_xor(acc.z, 16, 64); acc.w += __shfl_xor(acc.w, 16, 64); \
            acc.x += __shfl_xor(acc.x, 32, 64); acc.y += __shfl_xor(acc.y, 32, 64); \
            acc.z += __shfl_xor(acc.z, 32, 64); acc.w += __shfl_xor(acc.w, 32, 64);
        RED(accA)
        RED(accB)

        float sn = normv[n] * (1.0f - alpha);
        float4 f0a = feat04[(size_t)n * 16 + 2*r];
        float4 f0b = feat04[(size_t)n * 16 + 2*r + 1];
        float4 fsA, fsB;
        fsA.x = fmaf(accA.x, sn, f0a.x * alpha);
        fsA.y = fmaf(accA.y, sn, f0a.y * alpha);
        fsA.z = fmaf(accA.z, sn, f0a.z * alpha);
        fsA.w = fmaf(accA.w, sn, f0a.w * alpha);
        fsB.x = fmaf(accB.x, sn, f0b.x * alpha);
        fsB.y = fmaf(accB.y, sn, f0b.y * alpha);
        fsB.z = fmaf(accB.z, sn, f0b.z * alpha);
        fsB.w = fmaf(accB.w, sn, f0b.w * alpha);

        // res[d] = sum_k fs[k] * Wp[k][d]; group g covers k in [8g, 8g+8)
        float4 resA = make_float4(0.f, 0.f, 0.f, 0.f);
        float4 resB = make_float4(0.f, 0.f, 0.f, 0.f);
        int cidx = (2*r + 2*g) & 15;
        #pragma unroll
        for (int kk = 0; kk < 8; ++kk) {
            // k = 8g+kk; fs[k] lives on lane whose (lane&7)==g, comp kk -> lane g
            float fscomp = (kk == 0) ? fsA.x : (kk == 1) ? fsA.y : (kk == 2) ? fsA.z
                         : (kk == 3) ? fsA.w : (kk == 4) ? fsB.x : (kk == 5) ? fsB.y
                         : (kk == 6) ? fsB.z : fsB.w;
            float fsk = __shfl(fscomp, g, 64);
            int k4 = (8*g + kk) * 16;
            float4 wv0 = sW[k4 + cidx];
            float4 wv1 = sW[k4 + cidx + 1];
            resA.x = fmaf(fsk, wv0.x, resA.x); resA.y = fmaf(fsk, wv0.y, resA.y);
            resA.z = fmaf(fsk, wv0.z, resA.z); resA.w = fmaf(fsk, wv0.w, resA.w);
            resB.x = fmaf(fsk, wv1.x, resB.x); resB.y = fmaf(fsk, wv1.y, resB.y);
            resB.z = fmaf(fsk, wv1.z, resB.z); resB.w = fmaf(fsk, wv1.w, resB.w);
        }
        RED(resA)
        RED(resB)

        if (g == 0) {
            out4[(size_t)n * 16 + 2*r]     = resA;
            out4[(size_t)n * 16 + 2*r + 1] = resB;
        }
    }
}

// ---------------- last-resort fallback (atomic scatter path) ----------------

__global__ void deg_kernel(const int* __restrict__ dst, float* __restrict__ degs, int nE) {
    int i = blockIdx.x * blockDim.x + threadIdx.x;
    if (i < nE) atomAddF(&degs[dst[i]], 1.0f);
}

__global__ void norm_kernel(float* degs, int nN) {
    int i = blockIdx.x * blockDim.x + threadIdx.x;
    if (i < nN) degs[i] = rsqrtf(fmaxf(degs[i], 1.0f));
}

__global__ void wp_kernel(const float* __restrict__ W, const float* __restrict__ lamda_p,
                          const int* __restrict__ layer_p, float* __restrict__ Wp) {
    int i = blockIdx.x * blockDim.x + threadIdx.x;
    if (i < DDIM * DDIM) {
        float lam = lamda_p[0];
        int lb = layer_p[0];
        float layerf = (lb > 0 && lb < (1 << 23)) ? (float)lb : __int_as_float(lb);
        float beta = logf(lam / layerf + 1.0f);
        int k = i >> 6, d = i & 63;
        float w = beta * W[i];
        if (k == d) w += (1.0f - beta);
        Wp[i] = w;
    }
}

__global__ void scatter_kernel(const float* __restrict__ feat, const float* __restrict__ norm,
                               const int* __restrict__ src, const int* __restrict__ dst,
                               float* __restrict__ accum, int nE) {
    long long gid = (long long)blockIdx.x * blockDim.x + threadIdx.x;
    int e = (int)(gid >> 6);
    int d = (int)(gid & 63);
    if (e < nE) {
        int s = src[e];
        int t = dst[e];
        float v = feat[(size_t)s * DDIM + d] * norm[s];
        atomAddF(&accum[(size_t)t * DDIM + d], v);
    }
}

__global__ void final_kernel(float* __restrict__ out, const float* __restrict__ feat0,
                             const float* __restrict__ norm, const float* __restrict__ Wp,
                             const float* __restrict__ alpha_p, int nN) {
    __shared__ float sW[DDIM * DDIM];
    for (int i = threadIdx.x; i < DDIM * DDIM; i += blockDim.x) sW[i] = Wp[i];
    __syncthreads();
    float alpha = alpha_p[0];
    int lane = threadIdx.x & 63;
    int w = threadIdx.x >> 6;
    int wavesPerBlock = blockDim.x >> 6;
    int nGroups = (nN + wavesPerBlock - 1) / wavesPerBlock;
    for (int gi = blockIdx.x; gi < nGroups; gi += gridDim.x) {
        int n = gi * wavesPerBlock + w;
        bool valid = n < nN;
        float fs = 0.0f;
        if (valid) {
            fs = out[(size_t)n * DDIM + lane] * norm[n] * (1.0f - alpha)
               + feat0[(size_t)n * DDIM + lane] * alpha;
        }
        float acc = 0.0f;
        #pragma unroll
        for (int k = 0; k < DDIM; ++k) {
            float fsk = __shfl(fs, k, 64);
            acc = fmaf(fsk, sW[k * DDIM + lane], acc);
        }
        if (valid) out[(size_t)n * DDIM + lane] = acc;
    }
}

// ---------------- launch ----------------

static inline size_t align256(size_t x) { return (x + 255) & ~(size_t)255; }

extern "C" void kernel_launch(void* const* d_in, const int* in_sizes, int n_in,
                              void* d_out, int out_size, void* d_ws, size_t ws_size,
                              hipStream_t stream) {
    const float* feat  = (const float*)d_in[0];
    const float* feat0 = (const float*)d_in[1];
    const float* W     = (const float*)d_in[2];
    const int*   src   = (const int*)d_in[3];
    const int*   dst   = (const int*)d_in[4];
    const float* alpha = (const float*)d_in[5];
    const float* lamda = (const float*)d_in[6];
    const int*   layer = (const int*)d_in[7];
    float* out = (float*)d_out;

    int nN = in_sizes[0] / DDIM;
    int nE = in_sizes[3];
    int NS = (nN + 255) >> 8;
    int nb = (nN + SCAN_CHUNK - 1) / SCAN_CHUNK;

    // ---- new-path workspace layout ----
    size_t off = 0;
    size_t o_degI  = off; off += align256((size_t)nN * 4);
    size_t o_norm  = off; off += align256((size_t)nN * 4);
    size_t o_rowe  = off; off += align256((size_t)nN * 4);
    size_t o_sbase = off; off += align256((size_t)(NS + 1) * 4);
    size_t o_scnt  = off; off += align256((size_t)NS * 4);
    size_t o_wp    = off; off += align256((size_t)DDIM * DDIM * 4);
    size_t o_eidx  = off; off += align256((size_t)nE * 4);
    size_t base_sz = off;
    size_t o_featS = off; off += align256((size_t)nN * DDIM * 2);   // fp16 featS
    size_t need_t1 = off;                                 // staging aliased into featS
    size_t o_stag2 = base_sz;
    size_t need_t2 = base_sz + align256((size_t)nE * 4);  // staging separate, no featS

    bool newok = (NS >= 1 && NS <= MAXNS && nN <= (1 << 23));
    bool t1ok  = newok && ws_size >= need_t1 && ((size_t)nE * 4 <= (size_t)nN * DDIM * 2);
    bool t2ok  = newok && ws_size >= need_t2;

    if (t1ok || t2ok) {
        int*      degI  = (int*)  ((char*)d_ws + o_degI);
        float*    normv = (float*)((char*)d_ws + o_norm);
        int*      rowe  = (int*)  ((char*)d_ws + o_rowe);
        int*      sbase = (int*)  ((char*)d_ws + o_sbase);
        int*      scnt  = (int*)  ((char*)d_ws + o_scnt);
        float*    Wp    = (float*)((char*)d_ws + o_wp);
        int*      eidx  = (int*)  ((char*)d_ws + o_eidx);
        unsigned* stag  = (unsigned*)((char*)d_ws + (t1ok ? o_featS : o_stag2));
        float*    featS = (float*)((char*)d_ws + o_featS);

        hipMemsetAsync(scnt, 0, (size_t)NS * 4, stream);
        int pblocks = (nE + PART_EPB - 1) / PART_EPB;
        if (pblocks < 1) pblocks = 1;
        slice_count_kernel<<<pblocks, PART_TPB, 0, stream>>>(dst, scnt, nE, NS);
        slice_scan_wp_kernel<<<1, 512, 0, stream>>>(scnt, sbase, NS, nE, W, lamda, layer, Wp);
        partition_kernel<<<pblocks, PART_TPB, 0, stream>>>(src, dst, scnt, stag, nE, NS);
        bin_fill_kernel<<<NS, 256, 0, stream>>>(stag, sbase, degI, normv, rowe, eidx, nN);

        int gblocks = (nN + 3) / 4;
        if (gblocks > 8192) gblocks = 8192;
        if (t1ok) {
            // staging region dead after bin_fill; featS overwrites it (stream-ordered)
            scale_kernel<<<(nN + 15) / 16, 256, 0, stream>>>(
                (const float4*)feat, normv, (uint2*)featS, nN);
            gather_kernel<true><<<gblocks, 256, 0, stream>>>(
                (const void*)featS, (const float4*)feat0, normv, degI, rowe, eidx,
                Wp, alpha, (float4*)out, nN);
        } else {
            gather_kernel<false><<<gblocks, 256, 0, stream>>>(
                (const void*)feat, (const float4*)feat0, normv, degI, rowe, eidx,
                Wp, alpha, (float4*)out, nN);
        }
        return;
    }

    // ---- old CSR path (fallback) ----
    off = 0;
    size_t f_degI = off;      off += align256((size_t)nN * 4);
    size_t f_norm = off;      off += align256((size_t)nN * 4);
    size_t f_rows = off;      off += align256((size_t)nN * 4);
    size_t f_bsum = off;      off += align256((size_t)nb * 4);
    size_t f_wp   = off;      off += align256((size_t)DDIM * DDIM * 4);
    size_t f_eidx = off;      off += align256((size_t)nE * 4);
    size_t need_csr = off;
    size_t f_featS = off;     off += align256((size_t)nN * DDIM * 2);
    size_t need_full = off;

    if (ws_size >= need_csr && nb <= SCAN_BLOCK) {
        int*   degI  = (int*)  ((char*)d_ws + f_degI);
        float* normv = (float*)((char*)d_ws + f_norm);
        int*   rows  = (int*)  ((char*)d_ws + f_rows);
        int*   bsum  = (int*)  ((char*)d_ws + f_bsum);
        float* Wp    = (float*)((char*)d_ws + f_wp);
        int*   eidx  = (int*)  ((char*)d_ws + f_eidx);
        bool scaled = (ws_size >= need_full);
        float* featS = (float*)((char*)d_ws + f_featS);

        hipMemsetAsync(degI, 0, (size_t)nN * 4, stream);
        int e4blocks = ((nE + 3) / 4 + 255) / 256;
        deg_int_kernel<<<e4blocks, 256, 0, stream>>>(dst, degI, nE);
        scan1_kernel<<<nb, SCAN_BLOCK, 0, stream>>>(degI, rows, normv, bsum, nN);
        scan2_wp_kernel<<<1, SCAN_BLOCK, 0, stream>>>(bsum, nb, W, lamda, layer, Wp);
        if (scaled) {
            scan3_scale_kernel<<<(nN + 15) / 16, 256, 0, stream>>>(
                rows, bsum, (const float4*)feat, normv, (uint2*)featS, nN);
        } else {
            scan3_kernel<<<(nN + 255) / 256, 256, 0, stream>>>(rows, bsum, nN);
        }
        fill_kernel<<<e4blocks, 256, 0, stream>>>(src, dst, rows, eidx, nE);

        int gblocks = (nN + 3) / 4;
        if (gblocks > 8192) gblocks = 8192;
        if (scaled) {
            gather_kernel<true><<<gblocks, 256, 0, stream>>>(
                (const void*)featS, (const float4*)feat0, normv, degI, rows, eidx,
                Wp, alpha, (float4*)out, nN);
        } else {
            gather_kernel<false><<<gblocks, 256, 0, stream>>>(
                (const void*)feat, (const float4*)feat0, normv, degI, rows, eidx,
                Wp, alpha, (float4*)out, nN);
        }
    } else {
        float* degs = (float*)d_ws;
        size_t degs_bytes_al = align256((size_t)nN * 4);
        float* Wp = (float*)((char*)d_ws + degs_bytes_al);

        hipMemsetAsync(out, 0, (size_t)out_size * sizeof(float), stream);
        hipMemsetAsync(degs, 0, (size_t)nN * sizeof(float), stream);

        deg_kernel<<<(nE + 255) / 256, 256, 0, stream>>>(dst, degs, nE);
        norm_kernel<<<(nN + 255) / 256, 256, 0, stream>>>(degs, nN);
        wp_kernel<<<(DDIM * DDIM + 255) / 256, 256, 0, stream>>>(W, lamda, layer, Wp);

        long long tot = (long long)nE * DDIM;
        int sblocks = (int)((tot + 255) / 256);
        scatter_kernel<<<sblocks, 256, 0, stream>>>(feat, degs, src, dst, out, nE);
        final_kernel<<<2048, 256, 0, stream>>>(out, feat0, degs, Wp, alpha, nN);
    }
}